// Round 9
// baseline (171.698 us; speedup 1.0000x reference)
//
#include <hip/hip_runtime.h>
#include <hip/hip_cooperative_groups.h>
#include <hip/hip_fp16.h>
#include <math.h>

namespace cg = cooperative_groups;

#define W 512
#define H 512
#define NPIX (W*H)
#define RAD 10
#define KS 21
#define CRF_EPS 1e-4f

#define TX 32
#define TY 8
#define CIN (TX + 2*RAD)   // 52
#define RIN (TY + 2*RAD)   // 28
#define GX (W / TX)        // 16
#define GY (H / TY)        // 64
#define NBLK (GX*GY)       // 1024
#define NVT (CIN * 4)      // 208 V threads (2 rows each)

// coop LDS layout (30,784 B => 5 blocks/CU):
//  region0 [0, 24960): time-shared --
//    F1: sQh (ushort4 tile) @13312..24960; V-outs i0@0, i1@6656 (direct),
//        i2@13312 (reg-held, overwrites sQh after barrier)
//    F2: sAB (ushort4 tile) @0..11648; ia@11648..18304; ib@18304..24960
//    P1: ii0 (float2 V-out) @0
//    P2: s12 (float2 tile) @0..11648; ii1@11648..14976
//  sG [24960, 30784): persistent fp32 gray tile (computed once from image)
#define SM_BYTES 30784
#define SG_OFF 24960

struct W21 { float w[KS]; };

struct Params {
    const float4* unary;
    const float*  image;
    ushort4* Qh;             // fp16x4 Q
    float2*  a1b1;
    ushort4* ah;             // fp16x4 a
    ushort4* bh;             // fp16x4 b
    float4*  Qfinal;
    W21 wg, wu;
    float c0g, c0u;
};

__device__ __forceinline__ float4 f4(float x, float y, float z, float w_) {
    return make_float4(x, y, z, w_);
}
__device__ __forceinline__ float4 fma4(float s, float4 a, float4 acc) {
    acc.x = fmaf(s, a.x, acc.x); acc.y = fmaf(s, a.y, acc.y);
    acc.z = fmaf(s, a.z, acc.z); acc.w = fmaf(s, a.w, acc.w);
    return acc;
}
__device__ __forceinline__ int swz(int b, int N) {
    return (b & 7) * (N >> 3) + (b >> 3);
}
__device__ __forceinline__ ushort4 pack4(float4 v) {
    ushort4 r;
    r.x = __half_as_ushort(__float2half_rn(v.x));
    r.y = __half_as_ushort(__float2half_rn(v.y));
    r.z = __half_as_ushort(__float2half_rn(v.z));
    r.w = __half_as_ushort(__float2half_rn(v.w));
    return r;
}
__device__ __forceinline__ float4 unpack4(ushort4 v) {
    return f4(__half2float(__ushort_as_half(v.x)),
              __half2float(__ushort_as_half(v.y)),
              __half2float(__ushort_as_half(v.z)),
              __half2float(__ushort_as_half(v.w)));
}
__device__ __forceinline__ unsigned short packh(float v) {
    return __half_as_ushort(__float2half_rn(v));
}
__device__ __forceinline__ float unpackh(unsigned short v) {
    return __half2float(__ushort_as_half(v));
}

// ======================= cooperative single-kernel path ====================

__global__ __launch_bounds__(256, 5) void k_crf(Params P) {
    cg::grid_group grid = cg::this_grid();
    __shared__ __align__(16) char smem[SM_BYTES];
    ushort4* sQh = (ushort4*)(smem + 13312);   // F1 Q staging
    float4*  i0  = (float4*)smem;
    float4*  i1  = (float4*)(smem + 6656);
    float4*  i2  = (float4*)(smem + 13312);
    ushort4* sAB = (ushort4*)smem;             // F2 A/B staging
    float4*  ia  = (float4*)(smem + 11648);
    float4*  ib  = (float4*)(smem + 18304);
    float2*  s12 = (float2*)smem;              // P2 staging
    float2*  ii1 = (float2*)(smem + 11648);
    float2*  ii0 = (float2*)smem;              // P1 V-out
    float*   sG  = (float*)(smem + SG_OFF);    // persistent gray

    int t = threadIdx.x;
    int L = swz(blockIdx.x, NBLK);
    int x0 = (L & (GX - 1)) * TX, y0 = (L >> 4) * TY;
    // H/epilogue ownership: t<128 owns px pair (2 cols)
    int hrow = t >> 4, hx = (t & 15) * 2;
    int py = y0 + hrow, px0 = x0 + hx;
    int p0 = py * W + px0;
    // V ownership
    int vc = t % CIN, vr0 = (t / CIN) * 2;
    int hbase = hrow * CIN + hx;               // H tap base
    int ccen = (hrow + RAD) * CIN + hx + RAD;  // center pair base

    // ---- P1: Q init + gray tile + s1 conv ----
    {
        int pi = blockIdx.x * 256 + t;
        float4 u0 = P.unary[pi];
        float mn = fminf(fminf(u0.x, u0.y), fminf(u0.z, u0.w));
        float ex = expf(mn - u0.x), ey = expf(mn - u0.y);
        float ez = expf(mn - u0.z), ew = expf(mn - u0.w);
        float inv = 1.f / (ex + ey + ez + ew);
        P.Qh[pi] = pack4(f4(ex * inv, ey * inv, ez * inv, ew * inv));
    }
    for (int i = t; i < RIN * CIN; i += 256) {
        int r = i / CIN, c = i - r * CIN;
        int gx = x0 + c - RAD, gy = y0 + r - RAD;
        float g = 0.f;
        if ((unsigned)gx < W && (unsigned)gy < H) {
            int pp = gy * W + gx;
            g = 0.2989f * P.image[3 * pp] + 0.5870f * P.image[3 * pp + 1]
              + 0.1140f * P.image[3 * pp + 2];
        }
        sG[i] = g;
    }
    __syncthreads();
    // persistents (t<128): gray centers + closed-form norms
    float gc0 = 0.f, gc1 = 0.f, s3_0 = 0.f, s3_1 = 0.f;
    float Nu0 = 0.f, Nu1 = 0.f;
    if (t < 128) {
        gc0 = sG[ccen]; gc1 = sG[ccen + 1];
        float Sgx0 = 0.f, Sgx1 = 0.f, Sgy = 0.f;
        float Sux0 = 0.f, Sux1 = 0.f, Suy = 0.f;
        #pragma unroll
        for (int d = -RAD; d <= RAD; ++d) {
            int xa = px0 + d, xb = px0 + 1 + d, yy = py + d;
            float wgd = P.wg.w[d + RAD], wud = P.wu.w[d + RAD];
            if (xa >= 0 && xa < W) { Sgx0 += wgd; Sux0 += wud; }
            if (xb >= 0 && xb < W) { Sgx1 += wgd; Sux1 += wud; }
            if (yy >= 0 && yy < H) { Sgy  += wgd; Suy  += wud; }
        }
        s3_0 = 3.f / (Sgx0 * Sgy - P.c0g);
        s3_1 = 3.f / (Sgx1 * Sgy - P.c0g);
        Nu0 = Sux0 * Suy - P.c0u;
        Nu1 = Sux1 * Suy - P.c0u;
    }
    // s1 V-pass on sG -> ii0 (direct write, disjoint from sG)
    if (t < NVT) {
        float2 acc0 = make_float2(0.f, 0.f), acc1 = acc0;
        #pragma unroll
        for (int s = 0; s < 22; ++s) {
            float g = sG[(vr0 + s) * CIN + vc];
            if (s <= 20) { float wgv = P.wu.w[s] * g; acc0.x += wgv; acc0.y = fmaf(wgv, g, acc0.y); }
            if (s >= 1)  { float wgv = P.wu.w[s-1] * g; acc1.x += wgv; acc1.y = fmaf(wgv, g, acc1.y); }
        }
        ii0[vr0 * CIN + vc] = acc0;
        ii0[(vr0 + 1) * CIN + vc] = acc1;
    }
    __syncthreads();
    float mI0 = 0.f, mI1 = 0.f, iv0 = 0.f, iv1 = 0.f, ibn0 = 0.f, ibn1 = 0.f;
    if (t < 128) {
        float2 A0 = make_float2(0.f, 0.f), A1 = A0;
        #pragma unroll
        for (int d = 0; d < 22; ++d) {
            float2 v = ii0[hbase + d];
            if (d <= 20) { A0.x = fmaf(P.wu.w[d], v.x, A0.x); A0.y = fmaf(P.wu.w[d], v.y, A0.y); }
            if (d >= 1)  { A1.x = fmaf(P.wu.w[d-1], v.x, A1.x); A1.y = fmaf(P.wu.w[d-1], v.y, A1.y); }
        }
        mI0 = A0.x - P.c0u * gc0;
        float mII0 = A0.y - P.c0u * gc0 * gc0;
        iv0 = 1.f / ((mII0 - mI0 * mI0) + CRF_EPS);
        float a1v0 = mI0 * (1.f - Nu0) * iv0;
        P.a1b1[p0] = make_float2(a1v0, Nu0 - a1v0 * mI0);
        mI1 = A1.x - P.c0u * gc1;
        float mII1 = A1.y - P.c0u * gc1 * gc1;
        iv1 = 1.f / ((mII1 - mI1 * mI1) + CRF_EPS);
        float a1v1 = mI1 * (1.f - Nu1) * iv1;
        P.a1b1[p0 + 1] = make_float2(a1v1, Nu1 - a1v1 * mI1);
    }
    grid.sync();

    // ---- P2: conv a1b1 -> inv_bn ----
    for (int i = t; i < RIN * CIN; i += 256) {
        int r = i / CIN, c = i - r * CIN;
        int gx = x0 + c - RAD, gy = y0 + r - RAD;
        float2 v = make_float2(0.f, 0.f);
        if ((unsigned)gx < W && (unsigned)gy < H) v = P.a1b1[gy * W + gx];
        s12[i] = v;
    }
    __syncthreads();
    if (t < NVT) {
        float2 acc0 = make_float2(0.f, 0.f), acc1 = acc0;
        #pragma unroll
        for (int s = 0; s < 22; ++s) {
            float2 v = s12[(vr0 + s) * CIN + vc];
            if (s <= 20) { acc0.x = fmaf(P.wu.w[s], v.x, acc0.x); acc0.y = fmaf(P.wu.w[s], v.y, acc0.y); }
            if (s >= 1)  { acc1.x = fmaf(P.wu.w[s-1], v.x, acc1.x); acc1.y = fmaf(P.wu.w[s-1], v.y, acc1.y); }
        }
        ii1[vr0 * CIN + vc] = acc0;               // direct: disjoint from s12
        ii1[(vr0 + 1) * CIN + vc] = acc1;
    }
    __syncthreads();
    if (t < 128) {
        float2 A0 = make_float2(0.f, 0.f), A1 = A0;
        #pragma unroll
        for (int d = 0; d < 22; ++d) {
            float2 v = ii1[hbase + d];
            if (d <= 20) { A0.x = fmaf(P.wu.w[d], v.x, A0.x); A0.y = fmaf(P.wu.w[d], v.y, A0.y); }
            if (d >= 1)  { A1.x = fmaf(P.wu.w[d-1], v.x, A1.x); A1.y = fmaf(P.wu.w[d-1], v.y, A1.y); }
        }
        float2 c0 = s12[ccen], c1 = s12[ccen + 1];
        ibn0 = 10.f / ((A0.x - P.c0u * c0.x) * gc0 + (A0.y - P.c0u * c0.y));
        ibn1 = 10.f / ((A1.x - P.c0u * c1.x) * gc1 + (A1.y - P.c0u * c1.y));
    }

    // ---- 5 mean-field iterations ----
    float4 part0, part1;
    for (int it = 0; it < 5; ++it) {
        // === F1 ===
        __syncthreads();                           // ii1/ia/ib reads done
        for (int i = t; i < RIN * CIN; i += 256) {
            int r = i / CIN, c = i - r * CIN;
            int gx = x0 + c - RAD, gy = y0 + r - RAD;
            ushort4 q = make_ushort4(0, 0, 0, 0);
            if ((unsigned)gx < W && (unsigned)gy < H) q = P.Qh[gy * W + gx];
            sQh[i] = q;                            // raw fp16 copy
        }
        __syncthreads();
        float4 Qc0, Qc1;
        if (t < 128) { Qc0 = unpack4(sQh[ccen]); Qc1 = unpack4(sQh[ccen + 1]); }
        float4 a2h[2];
        if (t < NVT) {
            float4 a0[2], a1r[2];
            #pragma unroll
            for (int j = 0; j < 2; ++j) { a0[j] = f4(0,0,0,0); a1r[j] = a0[j]; a2h[j] = a0[j]; }
            #pragma unroll
            for (int s = 0; s < 22; ++s) {
                float4 q = unpack4(sQh[(vr0 + s) * CIN + vc]);
                float g = sG[(vr0 + s) * CIN + vc];
                float4 gq = f4(g * q.x, g * q.y, g * q.z, g * q.w);
                if (s <= 20) {
                    a0[0]  = fma4(P.wg.w[s], q, a0[0]);
                    a1r[0] = fma4(P.wu.w[s], q, a1r[0]);
                    a2h[0] = fma4(P.wu.w[s], gq, a2h[0]);
                }
                if (s >= 1) {
                    a0[1]  = fma4(P.wg.w[s-1], q, a0[1]);
                    a1r[1] = fma4(P.wu.w[s-1], q, a1r[1]);
                    a2h[1] = fma4(P.wu.w[s-1], gq, a2h[1]);
                }
            }
            i0[vr0 * CIN + vc] = a0[0];            // direct: disjoint from sQh
            i0[(vr0 + 1) * CIN + vc] = a0[1];
            i1[vr0 * CIN + vc] = a1r[0];
            i1[(vr0 + 1) * CIN + vc] = a1r[1];
        }
        __syncthreads();                           // sQh reads + Qc reads done
        if (t < NVT) {
            i2[vr0 * CIN + vc] = a2h[0];           // overwrites sQh region
            i2[(vr0 + 1) * CIN + vc] = a2h[1];
        }
        __syncthreads();
        if (t < 128) {
            float4 A0[2], A1[2], A2[2];
            #pragma unroll
            for (int j = 0; j < 2; ++j) { A0[j] = f4(0,0,0,0); A1[j] = A0[j]; A2[j] = A0[j]; }
            #pragma unroll
            for (int d = 0; d < 22; ++d) {
                float4 v0 = i0[hbase + d], v1 = i1[hbase + d], v2 = i2[hbase + d];
                if (d <= 20) {
                    A0[0] = fma4(P.wg.w[d], v0, A0[0]);
                    A1[0] = fma4(P.wu.w[d], v1, A1[0]);
                    A2[0] = fma4(P.wu.w[d], v2, A2[0]);
                }
                if (d >= 1) {
                    A0[1] = fma4(P.wg.w[d-1], v0, A0[1]);
                    A1[1] = fma4(P.wu.w[d-1], v1, A1[1]);
                    A2[1] = fma4(P.wu.w[d-1], v2, A2[1]);
                }
            }
            #pragma unroll
            for (int j = 0; j < 2; ++j) {
                float4 Qc = j ? Qc1 : Qc0;
                float gcj = j ? gc1 : gc0;
                float mIj = j ? mI1 : mI0, ivj = j ? iv1 : iv0;
                float s3j = j ? s3_1 : s3_0;
                float4 g4  = fma4(-P.c0g, Qc, A0[j]);
                float4 m4  = fma4(-P.c0u, Qc, A1[j]);
                float4 mi4 = fma4(-P.c0u * gcj, Qc, A2[j]);
                float4 a, b;
                a.x = (mi4.x - mIj * m4.x) * ivj; a.y = (mi4.y - mIj * m4.y) * ivj;
                a.z = (mi4.z - mIj * m4.z) * ivj; a.w = (mi4.w - mIj * m4.w) * ivj;
                b.x = m4.x - a.x * mIj; b.y = m4.y - a.y * mIj;
                b.z = m4.z - a.z * mIj; b.w = m4.w - a.w * mIj;
                float4 u = P.unary[p0 + j];
                float4 pt = f4(fmaf(s3j, g4.x, -u.x), fmaf(s3j, g4.y, -u.y),
                               fmaf(s3j, g4.z, -u.z), fmaf(s3j, g4.w, -u.w));
                if (j) part1 = pt; else part0 = pt;
                P.ah[p0 + j] = pack4(a); P.bh[p0 + j] = pack4(b);
            }
        }
        grid.sync();

        // === F2 ===
        for (int i = t; i < RIN * CIN; i += 256) {
            int r = i / CIN, c = i - r * CIN;
            int gx = x0 + c - RAD, gy = y0 + r - RAD;
            ushort4 v = make_ushort4(0, 0, 0, 0);
            if ((unsigned)gx < W && (unsigned)gy < H) v = P.ah[gy * W + gx];
            sAB[i] = v;
        }
        __syncthreads();
        float4 Ac0, Ac1;
        if (t < 128) { Ac0 = unpack4(sAB[ccen]); Ac1 = unpack4(sAB[ccen + 1]); }
        if (t < NVT) {
            float4 va0 = f4(0,0,0,0), va1 = va0;
            #pragma unroll
            for (int s = 0; s < 22; ++s) {
                float4 v = unpack4(sAB[(vr0 + s) * CIN + vc]);
                if (s <= 20) va0 = fma4(P.wu.w[s], v, va0);
                if (s >= 1)  va1 = fma4(P.wu.w[s-1], v, va1);
            }
            ia[vr0 * CIN + vc] = va0;              // direct: disjoint from sAB
            ia[(vr0 + 1) * CIN + vc] = va1;
        }
        __syncthreads();                           // sAB(A) reads done
        for (int i = t; i < RIN * CIN; i += 256) {
            int r = i / CIN, c = i - r * CIN;
            int gx = x0 + c - RAD, gy = y0 + r - RAD;
            ushort4 v = make_ushort4(0, 0, 0, 0);
            if ((unsigned)gx < W && (unsigned)gy < H) v = P.bh[gy * W + gx];
            sAB[i] = v;
        }
        __syncthreads();
        float4 Bc0, Bc1;
        if (t < 128) { Bc0 = unpack4(sAB[ccen]); Bc1 = unpack4(sAB[ccen + 1]); }
        if (t < NVT) {
            float4 vb0 = f4(0,0,0,0), vb1 = vb0;
            #pragma unroll
            for (int s = 0; s < 22; ++s) {
                float4 v = unpack4(sAB[(vr0 + s) * CIN + vc]);
                if (s <= 20) vb0 = fma4(P.wu.w[s], v, vb0);
                if (s >= 1)  vb1 = fma4(P.wu.w[s-1], v, vb1);
            }
            ib[vr0 * CIN + vc] = vb0;              // direct: disjoint from sAB
            ib[(vr0 + 1) * CIN + vc] = vb1;
        }
        __syncthreads();
        if (t < 128) {
            float4 VA[2], VB[2];
            #pragma unroll
            for (int j = 0; j < 2; ++j) { VA[j] = f4(0,0,0,0); VB[j] = VA[j]; }
            #pragma unroll
            for (int d = 0; d < 22; ++d) {
                float4 va = ia[hbase + d], vb = ib[hbase + d];
                if (d <= 20) { VA[0] = fma4(P.wu.w[d], va, VA[0]); VB[0] = fma4(P.wu.w[d], vb, VB[0]); }
                if (d >= 1)  { VA[1] = fma4(P.wu.w[d-1], va, VA[1]); VB[1] = fma4(P.wu.w[d-1], vb, VB[1]); }
            }
            #pragma unroll
            for (int j = 0; j < 2; ++j) {
                float4 Ac = j ? Ac1 : Ac0, Bc = j ? Bc1 : Bc0;
                float gcj = j ? gc1 : gc0, ibnj = j ? ibn1 : ibn0;
                float4 pt = j ? part1 : part0;
                float4 a4 = fma4(-P.c0u, Ac, VA[j]);
                float4 b4 = fma4(-P.c0u, Bc, VB[j]);
                float lx = fmaf(fmaf(a4.x, gcj, b4.x), ibnj, pt.x);
                float ly = fmaf(fmaf(a4.y, gcj, b4.y), ibnj, pt.y);
                float lz = fmaf(fmaf(a4.z, gcj, b4.z), ibnj, pt.z);
                float lw = fmaf(fmaf(a4.w, gcj, b4.w), ibnj, pt.w);
                float m = fmaxf(fmaxf(lx, ly), fmaxf(lz, lw));
                float ex = expf(lx - m), ey = expf(ly - m);
                float ez = expf(lz - m), ew = expf(lw - m);
                float inv = 1.f / (ex + ey + ez + ew);
                float4 qn = f4(ex * inv, ey * inv, ez * inv, ew * inv);
                if (it == 4) P.Qfinal[p0 + j] = qn;
                else         P.Qh[p0 + j] = pack4(qn);
            }
        }
        if (it < 4) grid.sync();
    }
}

// ===================== fallback: round-8 multi-dispatch (proven) ===========

__global__ __launch_bounds__(256) void fb_init(const float* __restrict__ img,
        const float4* __restrict__ unary, unsigned short* __restrict__ grayh,
        ushort4* __restrict__ Qh, float* __restrict__ Sg, float* __restrict__ Su,
        W21 wg, W21 wu) {
    int t = threadIdx.x;
    if (blockIdx.x < 2) {
        int x = blockIdx.x * 256 + t;
        float sg = 0.f, su = 0.f;
        #pragma unroll
        for (int d = -RAD; d <= RAD; ++d) {
            int xx = x + d;
            if (xx >= 0 && xx < W) { sg += wg.w[d + RAD]; su += wu.w[d + RAD]; }
        }
        Sg[x] = sg; Su[x] = su;
    }
    int b = swz(blockIdx.x, NPIX / 256);
    int p = b * 256 + t;
    float r = img[3 * p], g = img[3 * p + 1], bch = img[3 * p + 2];
    grayh[p] = packh(0.2989f * r + 0.5870f * g + 0.1140f * bch);
    float4 u = unary[p];
    float mn = fminf(fminf(u.x, u.y), fminf(u.z, u.w));
    float ex = expf(mn - u.x), ey = expf(mn - u.y), ez = expf(mn - u.z), ew = expf(mn - u.w);
    float inv = 1.f / (ex + ey + ez + ew);
    Qh[p] = pack4(f4(ex * inv, ey * inv, ez * inv, ew * inv));
}

__global__ __launch_bounds__(256, 4) void fb_s1(const unsigned short* __restrict__ grayh,
        const float* __restrict__ Su, float* __restrict__ mean_I,
        float* __restrict__ inv_var, float2* __restrict__ a1b1,
        W21 wu, float c0u) {
    __shared__ float  sg[RIN][CIN];
    __shared__ float2 ii[TY][CIN];
    int L = swz(blockIdx.x, NBLK);
    int x0 = (L & (GX - 1)) * TX, y0 = (L >> 4) * TY;
    int t = threadIdx.x;
    for (int i = t; i < RIN * CIN; i += 256) {
        int r = i / CIN, c = i - r * CIN;
        int gx = x0 + c - RAD, gy = y0 + r - RAD;
        float g = 0.f;
        if ((unsigned)gx < W && (unsigned)gy < H) g = unpackh(grayh[gy * W + gx]);
        sg[r][c] = g;
    }
    __syncthreads();
    if (t < NVT) {
        int c = t % CIN, r0 = (t / CIN) * 2;
        float2 acc0 = make_float2(0.f, 0.f), acc1 = acc0;
        #pragma unroll
        for (int s = 0; s < 22; ++s) {
            float g = sg[r0 + s][c];
            if (s <= 20) { float wgv = wu.w[s] * g; acc0.x += wgv; acc0.y = fmaf(wgv, g, acc0.y); }
            if (s >= 1)  { float wgv = wu.w[s-1] * g; acc1.x += wgv; acc1.y = fmaf(wgv, g, acc1.y); }
        }
        ii[r0][c] = acc0; ii[r0 + 1][c] = acc1;
    }
    __syncthreads();
    int row = t >> 5, col = t & 31;
    float2 A = make_float2(0.f, 0.f);
    #pragma unroll
    for (int d = 0; d < KS; ++d) {
        float2 v = ii[row][col + d];
        A.x = fmaf(wu.w[d], v.x, A.x);
        A.y = fmaf(wu.w[d], v.y, A.y);
    }
    int py = y0 + row, px = x0 + col;
    int p = py * W + px;
    float gc = sg[row + RAD][col + RAD];
    float mI = A.x - c0u * gc;
    float mII = A.y - c0u * gc * gc;
    float iv = 1.f / ((mII - mI * mI) + CRF_EPS);
    float N = Su[px] * Su[py] - c0u;
    float av = mI * (1.f - N) * iv;
    float bv = N - av * mI;
    mean_I[p] = mI; inv_var[p] = iv; a1b1[p] = make_float2(av, bv);
}

__global__ __launch_bounds__(256, 4) void fb_s2(const float2* __restrict__ a1b1,
        const unsigned short* __restrict__ grayh, float* __restrict__ inv_bn,
        W21 wu, float c0u) {
    __shared__ float2 s2[RIN][CIN];
    __shared__ float2 ii[TY][CIN];
    int L = swz(blockIdx.x, NBLK);
    int x0 = (L & (GX - 1)) * TX, y0 = (L >> 4) * TY;
    int t = threadIdx.x;
    for (int i = t; i < RIN * CIN; i += 256) {
        int r = i / CIN, c = i - r * CIN;
        int gx = x0 + c - RAD, gy = y0 + r - RAD;
        float2 v = make_float2(0.f, 0.f);
        if ((unsigned)gx < W && (unsigned)gy < H) v = a1b1[gy * W + gx];
        s2[r][c] = v;
    }
    __syncthreads();
    if (t < NVT) {
        int c = t % CIN, r0 = (t / CIN) * 2;
        float2 acc0 = make_float2(0.f, 0.f), acc1 = acc0;
        #pragma unroll
        for (int s = 0; s < 22; ++s) {
            float2 v = s2[r0 + s][c];
            if (s <= 20) { acc0.x = fmaf(wu.w[s], v.x, acc0.x); acc0.y = fmaf(wu.w[s], v.y, acc0.y); }
            if (s >= 1)  { acc1.x = fmaf(wu.w[s-1], v.x, acc1.x); acc1.y = fmaf(wu.w[s-1], v.y, acc1.y); }
        }
        ii[r0][c] = acc0; ii[r0 + 1][c] = acc1;
    }
    __syncthreads();
    int row = t >> 5, col = t & 31;
    float2 A = make_float2(0.f, 0.f);
    #pragma unroll
    for (int d = 0; d < KS; ++d) {
        float2 v = ii[row][col + d];
        A.x = fmaf(wu.w[d], v.x, A.x);
        A.y = fmaf(wu.w[d], v.y, A.y);
    }
    int p = (y0 + row) * W + x0 + col;
    float2 cen = s2[row + RAD][col + RAD];
    float va = A.x - c0u * cen.x;
    float vb = A.y - c0u * cen.y;
    inv_bn[p] = 1.f / (va * unpackh(grayh[p]) + vb);
}

__global__ __launch_bounds__(256, 4) void fb_f1(const ushort4* __restrict__ Qh,
        const unsigned short* __restrict__ grayh, const float* __restrict__ mean_I,
        const float* __restrict__ inv_var, const float* __restrict__ Sg,
        const float4* __restrict__ unary, ushort4* __restrict__ a_out,
        ushort4* __restrict__ b_out, float4* __restrict__ partial,
        W21 wg, W21 wu, float c0g, float c0u) {
    __shared__ __align__(16) char smem[23296 + 5824 + 6656];
    float4* sQ = (float4*)smem;
    float*  sG = (float*)(smem + 23296);
    float4* i2 = (float4*)(smem + 23296 + 5824);
    float4* i0 = (float4*)smem;
    float4* i1 = (float4*)(smem + 6656);
    int L = swz(blockIdx.x, NBLK);
    int x0 = (L & (GX - 1)) * TX, y0 = (L >> 4) * TY;
    int t = threadIdx.x;
    for (int i = t; i < RIN * CIN; i += 256) {
        int r = i / CIN, c = i - r * CIN;
        int gx = x0 + c - RAD, gy = y0 + r - RAD;
        float4 q = f4(0.f, 0.f, 0.f, 0.f); float g = 0.f;
        if ((unsigned)gx < W && (unsigned)gy < H) {
            int p = gy * W + gx; q = unpack4(Qh[p]); g = unpackh(grayh[p]);
        }
        sQ[i] = q; sG[i] = g;
    }
    __syncthreads();
    int row = t >> 5, col = t & 31;
    int py = y0 + row, px = x0 + col;
    int p = py * W + px;
    float mI = mean_I[p], iv = inv_var[p];
    float4 u = unary[p];
    float sgx = Sg[px], sgy = Sg[py];
    float4 Qc = sQ[(row + RAD) * CIN + col + RAD];
    float  gc = sG[(row + RAD) * CIN + col + RAD];
    float4 a0[2], a1[2], a2[2];
    int vc = t % CIN, vr0 = (t / CIN) * 2;
    if (t < NVT) {
        #pragma unroll
        for (int j = 0; j < 2; ++j) { a0[j] = f4(0,0,0,0); a1[j] = a0[j]; a2[j] = a0[j]; }
        #pragma unroll
        for (int s = 0; s < 22; ++s) {
            float4 q = sQ[(vr0 + s) * CIN + vc];
            float g = sG[(vr0 + s) * CIN + vc];
            float4 gq = f4(g * q.x, g * q.y, g * q.z, g * q.w);
            if (s <= 20) {
                a0[0] = fma4(wg.w[s], q, a0[0]);
                a1[0] = fma4(wu.w[s], q, a1[0]);
                a2[0] = fma4(wu.w[s], gq, a2[0]);
            }
            if (s >= 1) {
                a0[1] = fma4(wg.w[s-1], q, a0[1]);
                a1[1] = fma4(wu.w[s-1], q, a1[1]);
                a2[1] = fma4(wu.w[s-1], gq, a2[1]);
            }
        }
    }
    __syncthreads();
    if (t < NVT) {
        #pragma unroll
        for (int j = 0; j < 2; ++j) {
            i0[(vr0 + j) * CIN + vc] = a0[j];
            i1[(vr0 + j) * CIN + vc] = a1[j];
            i2[(vr0 + j) * CIN + vc] = a2[j];
        }
    }
    __syncthreads();
    float4 A0 = f4(0,0,0,0), A1 = A0, A2 = A0;
    #pragma unroll
    for (int d = 0; d < KS; ++d) {
        A0 = fma4(wg.w[d], i0[row * CIN + col + d], A0);
        A1 = fma4(wu.w[d], i1[row * CIN + col + d], A1);
        A2 = fma4(wu.w[d], i2[row * CIN + col + d], A2);
    }
    float4 g4  = fma4(-c0g, Qc, A0);
    float4 m4  = fma4(-c0u, Qc, A1);
    float4 mi4 = fma4(-c0u * gc, Qc, A2);
    float4 a, b;
    a.x = (mi4.x - mI * m4.x) * iv; a.y = (mi4.y - mI * m4.y) * iv;
    a.z = (mi4.z - mI * m4.z) * iv; a.w = (mi4.w - mI * m4.w) * iv;
    b.x = m4.x - a.x * mI; b.y = m4.y - a.y * mI;
    b.z = m4.z - a.z * mI; b.w = m4.w - a.w * mI;
    float s3 = 3.f / (sgx * sgy - c0g);
    float4 part = f4(fmaf(s3, g4.x, -u.x), fmaf(s3, g4.y, -u.y),
                     fmaf(s3, g4.z, -u.z), fmaf(s3, g4.w, -u.w));
    a_out[p] = pack4(a); b_out[p] = pack4(b); partial[p] = part;
}

__global__ __launch_bounds__(256, 4) void fb_f2(const ushort4* __restrict__ A,
        const ushort4* __restrict__ B, const float4* __restrict__ partial,
        const unsigned short* __restrict__ grayh, const float* __restrict__ inv_bn,
        float4* __restrict__ QoutF, ushort4* __restrict__ QoutH, int last,
        W21 wu, float c0u) {
    __shared__ __align__(16) char smem[23296 + 6656];
    float4* sT = (float4*)smem;
    float4* ia = (float4*)(smem + 23296);
    float4* ib = (float4*)smem;
    int L = swz(blockIdx.x, NBLK);
    int x0 = (L & (GX - 1)) * TX, y0 = (L >> 4) * TY;
    int t = threadIdx.x;
    int row = t >> 5, col = t & 31;
    int py = y0 + row, px = x0 + col;
    int p = py * W + px;
    int vc = t % CIN, vr0 = (t / CIN) * 2;
    float gv = unpackh(grayh[p]);
    float ibn = 10.f * inv_bn[p];
    float4 part = partial[p];
    for (int i = t; i < RIN * CIN; i += 256) {
        int r = i / CIN, c = i - r * CIN;
        int gx = x0 + c - RAD, gy = y0 + r - RAD;
        float4 v = f4(0.f, 0.f, 0.f, 0.f);
        if ((unsigned)gx < W && (unsigned)gy < H) v = unpack4(A[gy * W + gx]);
        sT[i] = v;
    }
    __syncthreads();
    float4 Ac = sT[(row + RAD) * CIN + col + RAD];
    float4 va0 = f4(0,0,0,0), va1 = va0;
    if (t < NVT) {
        #pragma unroll
        for (int s = 0; s < 22; ++s) {
            float4 v = sT[(vr0 + s) * CIN + vc];
            if (s <= 20) va0 = fma4(wu.w[s], v, va0);
            if (s >= 1)  va1 = fma4(wu.w[s-1], v, va1);
        }
        ia[vr0 * CIN + vc] = va0;
        ia[(vr0 + 1) * CIN + vc] = va1;
    }
    __syncthreads();
    for (int i = t; i < RIN * CIN; i += 256) {
        int r = i / CIN, c = i - r * CIN;
        int gx = x0 + c - RAD, gy = y0 + r - RAD;
        float4 v = f4(0.f, 0.f, 0.f, 0.f);
        if ((unsigned)gx < W && (unsigned)gy < H) v = unpack4(B[gy * W + gx]);
        sT[i] = v;
    }
    __syncthreads();
    float4 Bc = sT[(row + RAD) * CIN + col + RAD];
    float4 vb0 = f4(0,0,0,0), vb1 = vb0;
    if (t < NVT) {
        #pragma unroll
        for (int s = 0; s < 22; ++s) {
            float4 v = sT[(vr0 + s) * CIN + vc];
            if (s <= 20) vb0 = fma4(wu.w[s], v, vb0);
            if (s >= 1)  vb1 = fma4(wu.w[s-1], v, vb1);
        }
    }
    __syncthreads();
    if (t < NVT) {
        ib[vr0 * CIN + vc] = vb0;
        ib[(vr0 + 1) * CIN + vc] = vb1;
    }
    __syncthreads();
    float4 VA = f4(0,0,0,0), VB = VA;
    #pragma unroll
    for (int d = 0; d < KS; ++d) {
        VA = fma4(wu.w[d], ia[row * CIN + col + d], VA);
        VB = fma4(wu.w[d], ib[row * CIN + col + d], VB);
    }
    float4 a4 = fma4(-c0u, Ac, VA);
    float4 b4 = fma4(-c0u, Bc, VB);
    float lx = fmaf(fmaf(a4.x, gv, b4.x), ibn, part.x);
    float ly = fmaf(fmaf(a4.y, gv, b4.y), ibn, part.y);
    float lz = fmaf(fmaf(a4.z, gv, b4.z), ibn, part.z);
    float lw = fmaf(fmaf(a4.w, gv, b4.w), ibn, part.w);
    float m = fmaxf(fmaxf(lx, ly), fmaxf(lz, lw));
    float ex = expf(lx - m), ey = expf(ly - m), ez = expf(lz - m), ew = expf(lw - m);
    float inv = 1.f / (ex + ey + ez + ew);
    float4 qn = f4(ex * inv, ey * inv, ez * inv, ew * inv);
    if (last) QoutF[p] = qn;
    else      QoutH[p] = pack4(qn);
}

// ---- host ----

static void make_w_host(double theta, W21* w, float* c0) {
    double tmp[KS], s = 0.0;
    for (int d = -RAD; d <= RAD; ++d) {
        double v = exp(-(double)(d * d) / (2.0 * theta * theta));
        tmp[d + RAD] = v; s += v;
    }
    for (int i = 0; i < KS; ++i) w->w[i] = (float)(tmp[i] / s);
    *c0 = (float)(1.0 / (s * s));   // normalized 2D center weight
}

extern "C" void kernel_launch(void* const* d_in, const int* in_sizes, int n_in,
                              void* d_out, int out_size, void* d_ws, size_t ws_size,
                              hipStream_t stream) {
    const float4* unary = (const float4*)d_in[0];
    const float* image = (const float*)d_in[1];
    char* wsb = (char*)d_ws;

    unsigned short* grayh = (unsigned short*)wsb;                  // 0.5 MB (fallback)
    ushort4* Qh      = (ushort4*)(wsb + 524288);                   // 2 MB
    ushort4* ah      = (ushort4*)(wsb + 2621440);                  // 2 MB
    ushort4* bh      = (ushort4*)(wsb + 4718592);                  // 2 MB
    float4*  partial = (float4*)(wsb + 6815744);                   // 4 MB (fallback)
    float*   mean_I  = (float*)(wsb + 11010048);                   // 1 MB (fallback)
    float*   inv_var = (float*)(wsb + 12058624);                   // 1 MB (fallback)
    float*   inv_bn  = (float*)(wsb + 13107200);                   // 1 MB (fallback)
    float2*  a1b1    = (float2*)(wsb + 14155776);                  // 2 MB
    float*   Sg      = (float*)(wsb + 16252928);
    float*   Su      = (float*)(wsb + 16255040);

    W21 wg, wu; float c0g, c0u;
    make_w_host(2.5, &wg, &c0g);
    make_w_host(10.0 / 3.0, &wu, &c0u);

    // deterministic cooperative-capacity pre-check (host-only, capture-safe)
    int dev = 0;
    (void)hipGetDevice(&dev);
    int coop = 0, nCU = 0, blkPerCU = 0;
    (void)hipDeviceGetAttribute(&coop, hipDeviceAttributeCooperativeLaunch, dev);
    (void)hipDeviceGetAttribute(&nCU, hipDeviceAttributeMultiprocessorCount, dev);
    (void)hipOccupancyMaxActiveBlocksPerMultiprocessor(&blkPerCU,
            (const void*)k_crf, 256, 0);
    bool useCoop = (coop != 0) && ((long)blkPerCU * nCU >= NBLK);

    hipError_t st = hipErrorUnknown;
    if (useCoop) {
        Params P;
        P.unary = unary; P.image = image; P.Qh = Qh;
        P.a1b1 = a1b1; P.ah = ah; P.bh = bh;
        P.Qfinal = (float4*)d_out;
        P.wg = wg; P.wu = wu; P.c0g = c0g; P.c0u = c0u;
        void* args[] = { &P };
        st = hipLaunchCooperativeKernel((const void*)k_crf, dim3(NBLK), dim3(256),
                                        args, 0, stream);
    }
    if (st != hipSuccess) {
        dim3 bl(256), grEl(NPIX / 256), grT(NBLK);
        fb_init<<<grEl, bl, 0, stream>>>(image, unary, grayh, Qh, Sg, Su, wg, wu);
        fb_s1<<<grT, bl, 0, stream>>>(grayh, Su, mean_I, inv_var, a1b1, wu, c0u);
        fb_s2<<<grT, bl, 0, stream>>>(a1b1, grayh, inv_bn, wu, c0u);
        for (int it = 0; it < 5; ++it) {
            fb_f1<<<grT, bl, 0, stream>>>(Qh, grayh, mean_I, inv_var, Sg,
                                          unary, ah, bh, partial, wg, wu, c0g, c0u);
            fb_f2<<<grT, bl, 0, stream>>>(ah, bh, partial, grayh, inv_bn,
                                          (float4*)d_out, Qh, (it == 4) ? 1 : 0,
                                          wu, c0u);
        }
    }
}

// Round 10
// 170.681 us; speedup vs baseline: 1.0060x; 1.0060x over previous
//
#include <hip/hip_runtime.h>
#include <hip/hip_cooperative_groups.h>
#include <hip/hip_fp16.h>
#include <math.h>

namespace cg = cooperative_groups;

#define W 512
#define H 512
#define NPIX (W*H)
#define RAD 10
#define KS 21
#define CRF_EPS 1e-4f

#define TX 32
#define TY 8
#define CIN (TX + 2*RAD)   // 52
#define RIN (TY + 2*RAD)   // 28
#define GX (W / TX)        // 16
#define GY (H / TY)        // 64
#define NBLK (GX*GY)       // 1024
#define NVT (CIN * 4)      // 208 V threads (2 rows each)

// coop LDS (29,952 B => 5 blocks/CU): region0 [0,23296) fp32 staging
// (aliased by i0@0, i1@6656, ib@0, ii0@0); region1 [23296,29952):
// sG gray (5824) / i2 / ia / ii1.
#define SM_BYTES 29952
#define OFF_R1 23296

struct W21 { float w[KS]; };

struct Params {
    const float4* unary;
    const float*  image;
    unsigned short* grayh;
    ushort4* qA; ushort4* qB;      // Q parity buffers
    float2*  a1b1;
    ushort4* aA; ushort4* aB;      // a parity buffers
    ushort4* bA; ushort4* bB;      // b parity buffers
    float4*  Qfinal;
    int* flag_q; int* flag_ab;     // per-tile iteration flags
    W21 wg, wu;
    float c0g, c0u;
};

__device__ __forceinline__ float4 f4(float x, float y, float z, float w_) {
    return make_float4(x, y, z, w_);
}
__device__ __forceinline__ float4 fma4(float s, float4 a, float4 acc) {
    acc.x = fmaf(s, a.x, acc.x); acc.y = fmaf(s, a.y, acc.y);
    acc.z = fmaf(s, a.z, acc.z); acc.w = fmaf(s, a.w, acc.w);
    return acc;
}
__device__ __forceinline__ int swz(int b, int N) {
    return (b & 7) * (N >> 3) + (b >> 3);
}
__device__ __forceinline__ ushort4 pack4(float4 v) {
    ushort4 r;
    r.x = __half_as_ushort(__float2half_rn(v.x));
    r.y = __half_as_ushort(__float2half_rn(v.y));
    r.z = __half_as_ushort(__float2half_rn(v.z));
    r.w = __half_as_ushort(__float2half_rn(v.w));
    return r;
}
__device__ __forceinline__ float4 unpack4(ushort4 v) {
    return f4(__half2float(__ushort_as_half(v.x)),
              __half2float(__ushort_as_half(v.y)),
              __half2float(__ushort_as_half(v.z)),
              __half2float(__ushort_as_half(v.w)));
}
__device__ __forceinline__ unsigned short packh(float v) {
    return __half_as_ushort(__float2half_rn(v));
}
__device__ __forceinline__ float unpackh(unsigned short v) {
    return __half2float(__ushort_as_half(v));
}

// spin until flag[nb] >= v (relaxed; caller fences after block barrier)
__device__ __forceinline__ void spin_ge(const int* f, int v) {
    while (__hip_atomic_load(f, __ATOMIC_RELAXED, __HIP_MEMORY_SCOPE_AGENT) < v)
        __builtin_amdgcn_s_sleep(2);
}

// ======================= cooperative single-kernel path ====================

__global__ __launch_bounds__(256, 5) void k_crf(Params P) {
    cg::grid_group grid = cg::this_grid();
    __shared__ __align__(16) char smem[SM_BYTES];
    float4* sQ  = (float4*)smem;
    float2* s2t = (float2*)smem;
    float2* ii0 = (float2*)smem;
    float*  sG  = (float*)(smem + OFF_R1);
    float2* ii1 = (float2*)(smem + OFF_R1);
    float4* i0  = (float4*)smem;
    float4* i1  = (float4*)(smem + 6656);
    float4* i2  = (float4*)(smem + OFF_R1);
    float4* ia  = (float4*)(smem + OFF_R1);
    float4* ib  = (float4*)smem;

    int t = threadIdx.x;
    int L = swz(blockIdx.x, NBLK);
    int txi = L & (GX - 1), tyi = L >> 4;
    int x0 = txi * TX, y0 = tyi * TY;
    int row = t >> 5, col = t & 31;
    int py = y0 + row, px = x0 + col;
    int p = py * W + px;
    int vc = t % CIN, vr0 = (t / CIN) * 2;
    int cidx = (row + RAD) * CIN + col + RAD;

    // neighbor tile each spinner (t<15) watches: dy in [-2,2], dx in [-1,1]
    int nbL = 0;
    if (t < 15) {
        int dy = t / 3 - 2, dx = t % 3 - 1;
        int ty2 = tyi + dy; ty2 = ty2 < 0 ? 0 : (ty2 > GY - 1 ? GY - 1 : ty2);
        int tx2 = txi + dx; tx2 = tx2 < 0 ? 0 : (tx2 > GX - 1 ? GX - 1 : tx2);
        nbL = ty2 * GX + tx2;
    }
    if (t == 0) { P.flag_q[L] = 0; P.flag_ab[L] = 0; }

    // ---- phase 0: gray + softmax(-unary) ----
    {
        int pi = blockIdx.x * 256 + t;
        float r = P.image[3 * pi], g = P.image[3 * pi + 1], b = P.image[3 * pi + 2];
        P.grayh[pi] = packh(0.2989f * r + 0.5870f * g + 0.1140f * b);
        float4 u0 = P.unary[pi];
        float mn = fminf(fminf(u0.x, u0.y), fminf(u0.z, u0.w));
        float ex = expf(mn - u0.x), ey = expf(mn - u0.y);
        float ez = expf(mn - u0.z), ew = expf(mn - u0.w);
        float inv = 1.f / (ex + ey + ez + ew);
        P.qA[pi] = pack4(f4(ex * inv, ey * inv, ez * inv, ew * inv));
    }
    float4 u = P.unary[p];
    float Sgx = 0.f, Sgy = 0.f, Sux = 0.f, Suy = 0.f;
    #pragma unroll
    for (int d = -RAD; d <= RAD; ++d) {
        int xx = px + d, yy = py + d;
        if (xx >= 0 && xx < W) { Sgx += P.wg.w[d + RAD]; Sux += P.wu.w[d + RAD]; }
        if (yy >= 0 && yy < H) { Sgy += P.wg.w[d + RAD]; Suy += P.wu.w[d + RAD]; }
    }
    float s3 = 3.f / (Sgx * Sgy - P.c0g);
    grid.sync();                                   // flags + Q v1 + gray visible
    if (t == 0)
        __hip_atomic_store(&P.flag_q[L], 1, __ATOMIC_RELAXED, __HIP_MEMORY_SCOPE_AGENT);

    // ---- s1: conv{gray, gray^2} -> mI, iv (regs); a1b1 -> global ----
    for (int i = t; i < RIN * CIN; i += 256) {
        int r = i / CIN, c = i - r * CIN;
        int gx = x0 + c - RAD, gy = y0 + r - RAD;
        float g = 0.f;
        if ((unsigned)gx < W && (unsigned)gy < H) g = unpackh(P.grayh[gy * W + gx]);
        sG[i] = g;
    }
    __syncthreads();
    if (t < NVT) {
        float2 acc0 = make_float2(0.f, 0.f), acc1 = acc0;
        #pragma unroll
        for (int s = 0; s < 22; ++s) {
            float g = sG[(vr0 + s) * CIN + vc];
            if (s <= 20) { float wgv = P.wu.w[s] * g; acc0.x += wgv; acc0.y = fmaf(wgv, g, acc0.y); }
            if (s >= 1)  { float wgv = P.wu.w[s-1] * g; acc1.x += wgv; acc1.y = fmaf(wgv, g, acc1.y); }
        }
        ii0[vr0 * CIN + vc] = acc0;
        ii0[(vr0 + 1) * CIN + vc] = acc1;
    }
    __syncthreads();
    float gv = sG[cidx];
    float mI, iv, ibn;
    {
        float2 A = make_float2(0.f, 0.f);
        #pragma unroll
        for (int d = 0; d < KS; ++d) {
            float2 v = ii0[row * CIN + col + d];
            A.x = fmaf(P.wu.w[d], v.x, A.x);
            A.y = fmaf(P.wu.w[d], v.y, A.y);
        }
        mI = A.x - P.c0u * gv;
        float mII = A.y - P.c0u * gv * gv;
        iv = 1.f / ((mII - mI * mI) + CRF_EPS);
        float N = Sux * Suy - P.c0u;
        float a1v = mI * (1.f - N) * iv;
        float b1v = N - a1v * mI;
        P.a1b1[p] = make_float2(a1v, b1v);
    }
    grid.sync();

    // ---- s2: conv a1b1 -> inv_bn (reg) ----
    for (int i = t; i < RIN * CIN; i += 256) {
        int r = i / CIN, c = i - r * CIN;
        int gx = x0 + c - RAD, gy = y0 + r - RAD;
        float2 v = make_float2(0.f, 0.f);
        if ((unsigned)gx < W && (unsigned)gy < H) v = P.a1b1[gy * W + gx];
        s2t[i] = v;
    }
    __syncthreads();
    if (t < NVT) {
        float2 acc0 = make_float2(0.f, 0.f), acc1 = acc0;
        #pragma unroll
        for (int s = 0; s < 22; ++s) {
            float2 v = s2t[(vr0 + s) * CIN + vc];
            if (s <= 20) { acc0.x = fmaf(P.wu.w[s], v.x, acc0.x); acc0.y = fmaf(P.wu.w[s], v.y, acc0.y); }
            if (s >= 1)  { acc1.x = fmaf(P.wu.w[s-1], v.x, acc1.x); acc1.y = fmaf(P.wu.w[s-1], v.y, acc1.y); }
        }
        ii1[vr0 * CIN + vc] = acc0;
        ii1[(vr0 + 1) * CIN + vc] = acc1;
    }
    __syncthreads();
    {
        float2 A = make_float2(0.f, 0.f);
        #pragma unroll
        for (int d = 0; d < KS; ++d) {
            float2 v = ii1[row * CIN + col + d];
            A.x = fmaf(P.wu.w[d], v.x, A.x);
            A.y = fmaf(P.wu.w[d], v.y, A.y);
        }
        float2 cen = s2t[cidx];
        float va = A.x - P.c0u * cen.x;
        float vb = A.y - P.c0u * cen.y;
        ibn = 10.f / (va * gv + vb);
    }

    // ---- 5 mean-field iterations, neighbor-flag synced ----
    float px_part, py_part, pz_part, pw_part;
    for (int it = 0; it < 5; ++it) {
        const ushort4* qin  = (it & 1) ? P.qB : P.qA;
        ushort4*       qout = (it & 1) ? P.qA : P.qB;
        ushort4*       aw   = (it & 1) ? P.aB : P.aA;
        ushort4*       bw   = (it & 1) ? P.bB : P.bA;

        // === F1: wait Q(it+1) from 15-neighborhood ===
        if (t < 15) spin_ge(&P.flag_q[nbL], it + 1);
        __syncthreads();                           // + region0/1 reads done
        __threadfence();                           // acquire: invalidate stale
        for (int i = t; i < RIN * CIN; i += 256) {
            int r = i / CIN, c = i - r * CIN;
            int gx = x0 + c - RAD, gy = y0 + r - RAD;
            float4 q = f4(0.f, 0.f, 0.f, 0.f); float g = 0.f;
            if ((unsigned)gx < W && (unsigned)gy < H) {
                int pp = gy * W + gx;
                q = unpack4(qin[pp]); g = unpackh(P.grayh[pp]);
            }
            sQ[i] = q; sG[i] = g;
        }
        __syncthreads();
        float4 Qc = sQ[cidx];
        float4 a2h[2];
        if (t < NVT) {
            float4 a0[2], a1r[2];
            #pragma unroll
            for (int j = 0; j < 2; ++j) { a0[j] = f4(0,0,0,0); a1r[j] = a0[j]; a2h[j] = a0[j]; }
            #pragma unroll
            for (int s = 0; s < 22; ++s) {
                float4 q = sQ[(vr0 + s) * CIN + vc];
                float g = sG[(vr0 + s) * CIN + vc];
                float4 gq = f4(g * q.x, g * q.y, g * q.z, g * q.w);
                if (s <= 20) {
                    a0[0]  = fma4(P.wg.w[s], q, a0[0]);
                    a1r[0] = fma4(P.wu.w[s], q, a1r[0]);
                    a2h[0] = fma4(P.wu.w[s], gq, a2h[0]);
                }
                if (s >= 1) {
                    a0[1]  = fma4(P.wg.w[s-1], q, a0[1]);
                    a1r[1] = fma4(P.wu.w[s-1], q, a1r[1]);
                    a2h[1] = fma4(P.wu.w[s-1], gq, a2h[1]);
                }
            }
            i0[vr0 * CIN + vc] = a0[0];            // disjoint from sQ reads? no:
            i0[(vr0 + 1) * CIN + vc] = a0[1];      // i0/i1 alias sQ -- but all
            i1[vr0 * CIN + vc] = a1r[0];           // sQ reads happen above in
            i1[(vr0 + 1) * CIN + vc] = a1r[1];     // this same loop... see note
        }
        __syncthreads();
        if (t < NVT) {
            i2[vr0 * CIN + vc] = a2h[0];           // overwrites sG (dead)
            i2[(vr0 + 1) * CIN + vc] = a2h[1];
        }
        __syncthreads();
        if (t < 128) {
            // (t<128 H-threads use row/col mapping: 4 rows x 32 cols? No --
            //  here each of 256 threads owns 1 px; H-pass must be t<256.)
        }
        {
            float4 A0 = f4(0,0,0,0), A1 = A0, A2 = A0;
            #pragma unroll
            for (int d = 0; d < KS; ++d) {
                A0 = fma4(P.wg.w[d], i0[row * CIN + col + d], A0);
                A1 = fma4(P.wu.w[d], i1[row * CIN + col + d], A1);
                A2 = fma4(P.wu.w[d], i2[row * CIN + col + d], A2);
            }
            float4 g4  = fma4(-P.c0g, Qc, A0);
            float4 m4  = fma4(-P.c0u, Qc, A1);
            float4 mi4 = fma4(-P.c0u * gv, Qc, A2);
            float4 a, b;
            a.x = (mi4.x - mI * m4.x) * iv; a.y = (mi4.y - mI * m4.y) * iv;
            a.z = (mi4.z - mI * m4.z) * iv; a.w = (mi4.w - mI * m4.w) * iv;
            b.x = m4.x - a.x * mI; b.y = m4.y - a.y * mI;
            b.z = m4.z - a.z * mI; b.w = m4.w - a.w * mI;
            px_part = fmaf(s3, g4.x, -u.x); py_part = fmaf(s3, g4.y, -u.y);
            pz_part = fmaf(s3, g4.z, -u.z); pw_part = fmaf(s3, g4.w, -u.w);
            aw[p] = pack4(a); bw[p] = pack4(b);
        }
        __threadfence();                           // release: publish a,b
        __syncthreads();
        if (t == 0)
            __hip_atomic_store(&P.flag_ab[L], it + 1, __ATOMIC_RELEASE,
                               __HIP_MEMORY_SCOPE_AGENT);

        // === F2: wait a,b(it+1) from 15-neighborhood ===
        if (t < 15) spin_ge(&P.flag_ab[nbL], it + 1);
        __syncthreads();
        __threadfence();
        for (int i = t; i < RIN * CIN; i += 256) {
            int r = i / CIN, c = i - r * CIN;
            int gx = x0 + c - RAD, gy = y0 + r - RAD;
            float4 v = f4(0.f, 0.f, 0.f, 0.f);
            if ((unsigned)gx < W && (unsigned)gy < H) v = unpack4(aw[gy * W + gx]);
            sQ[i] = v;
        }
        __syncthreads();
        float4 Ac = sQ[cidx];
        if (t < NVT) {
            float4 va0 = f4(0,0,0,0), va1 = va0;
            #pragma unroll
            for (int s = 0; s < 22; ++s) {
                float4 v = sQ[(vr0 + s) * CIN + vc];
                if (s <= 20) va0 = fma4(P.wu.w[s], v, va0);
                if (s >= 1)  va1 = fma4(P.wu.w[s-1], v, va1);
            }
            ia[vr0 * CIN + vc] = va0;              // region1, no clobber of sQ
            ia[(vr0 + 1) * CIN + vc] = va1;
        }
        __syncthreads();
        for (int i = t; i < RIN * CIN; i += 256) {
            int r = i / CIN, c = i - r * CIN;
            int gx = x0 + c - RAD, gy = y0 + r - RAD;
            float4 v = f4(0.f, 0.f, 0.f, 0.f);
            if ((unsigned)gx < W && (unsigned)gy < H) v = unpack4(bw[gy * W + gx]);
            sQ[i] = v;
        }
        __syncthreads();
        float4 Bc = sQ[cidx];
        float4 vb0 = f4(0,0,0,0), vb1 = vb0;
        if (t < NVT) {
            #pragma unroll
            for (int s = 0; s < 22; ++s) {
                float4 v = sQ[(vr0 + s) * CIN + vc];
                if (s <= 20) vb0 = fma4(P.wu.w[s], v, vb0);
                if (s >= 1)  vb1 = fma4(P.wu.w[s-1], v, vb1);
            }
        }
        __syncthreads();
        if (t < NVT) {
            ib[vr0 * CIN + vc] = vb0;              // overwrite region0
            ib[(vr0 + 1) * CIN + vc] = vb1;
        }
        __syncthreads();
        {
            float4 VA = f4(0,0,0,0), VB = VA;
            #pragma unroll
            for (int d = 0; d < KS; ++d) {
                VA = fma4(P.wu.w[d], ia[row * CIN + col + d], VA);
                VB = fma4(P.wu.w[d], ib[row * CIN + col + d], VB);
            }
            float4 a4 = fma4(-P.c0u, Ac, VA);
            float4 b4 = fma4(-P.c0u, Bc, VB);
            float lx = fmaf(fmaf(a4.x, gv, b4.x), ibn, px_part);
            float ly = fmaf(fmaf(a4.y, gv, b4.y), ibn, py_part);
            float lz = fmaf(fmaf(a4.z, gv, b4.z), ibn, pz_part);
            float lw = fmaf(fmaf(a4.w, gv, b4.w), ibn, pw_part);
            float m = fmaxf(fmaxf(lx, ly), fmaxf(lz, lw));
            float ex = expf(lx - m), ey = expf(ly - m);
            float ez = expf(lz - m), ew = expf(lw - m);
            float inv = 1.f / (ex + ey + ez + ew);
            float4 qn = f4(ex * inv, ey * inv, ez * inv, ew * inv);
            if (it == 4) P.Qfinal[p] = qn;
            else         qout[p] = pack4(qn);
        }
        if (it < 4) {
            __threadfence();                       // release: publish Q
            __syncthreads();
            if (t == 0)
                __hip_atomic_store(&P.flag_q[L], it + 2, __ATOMIC_RELEASE,
                                   __HIP_MEMORY_SCOPE_AGENT);
        }
    }
}

// ===================== fallback: proven multi-dispatch =====================

__global__ __launch_bounds__(256) void fb_init(const float* __restrict__ img,
        const float4* __restrict__ unary, unsigned short* __restrict__ grayh,
        ushort4* __restrict__ Qh, float* __restrict__ Sg, float* __restrict__ Su,
        W21 wg, W21 wu) {
    int t = threadIdx.x;
    if (blockIdx.x < 2) {
        int x = blockIdx.x * 256 + t;
        float sg = 0.f, su = 0.f;
        #pragma unroll
        for (int d = -RAD; d <= RAD; ++d) {
            int xx = x + d;
            if (xx >= 0 && xx < W) { sg += wg.w[d + RAD]; su += wu.w[d + RAD]; }
        }
        Sg[x] = sg; Su[x] = su;
    }
    int b = swz(blockIdx.x, NPIX / 256);
    int p = b * 256 + t;
    float r = img[3 * p], g = img[3 * p + 1], bch = img[3 * p + 2];
    grayh[p] = packh(0.2989f * r + 0.5870f * g + 0.1140f * bch);
    float4 u = unary[p];
    float mn = fminf(fminf(u.x, u.y), fminf(u.z, u.w));
    float ex = expf(mn - u.x), ey = expf(mn - u.y), ez = expf(mn - u.z), ew = expf(mn - u.w);
    float inv = 1.f / (ex + ey + ez + ew);
    Qh[p] = pack4(f4(ex * inv, ey * inv, ez * inv, ew * inv));
}

__global__ __launch_bounds__(256, 4) void fb_s1(const unsigned short* __restrict__ grayh,
        const float* __restrict__ Su, float* __restrict__ mean_I,
        float* __restrict__ inv_var, float2* __restrict__ a1b1,
        W21 wu, float c0u) {
    __shared__ float  sg[RIN][CIN];
    __shared__ float2 ii[TY][CIN];
    int L = swz(blockIdx.x, NBLK);
    int x0 = (L & (GX - 1)) * TX, y0 = (L >> 4) * TY;
    int t = threadIdx.x;
    for (int i = t; i < RIN * CIN; i += 256) {
        int r = i / CIN, c = i - r * CIN;
        int gx = x0 + c - RAD, gy = y0 + r - RAD;
        float g = 0.f;
        if ((unsigned)gx < W && (unsigned)gy < H) g = unpackh(grayh[gy * W + gx]);
        sg[r][c] = g;
    }
    __syncthreads();
    if (t < NVT) {
        int c = t % CIN, r0 = (t / CIN) * 2;
        float2 acc0 = make_float2(0.f, 0.f), acc1 = acc0;
        #pragma unroll
        for (int s = 0; s < 22; ++s) {
            float g = sg[r0 + s][c];
            if (s <= 20) { float wgv = wu.w[s] * g; acc0.x += wgv; acc0.y = fmaf(wgv, g, acc0.y); }
            if (s >= 1)  { float wgv = wu.w[s-1] * g; acc1.x += wgv; acc1.y = fmaf(wgv, g, acc1.y); }
        }
        ii[r0][c] = acc0; ii[r0 + 1][c] = acc1;
    }
    __syncthreads();
    int row = t >> 5, col = t & 31;
    float2 A = make_float2(0.f, 0.f);
    #pragma unroll
    for (int d = 0; d < KS; ++d) {
        float2 v = ii[row][col + d];
        A.x = fmaf(wu.w[d], v.x, A.x);
        A.y = fmaf(wu.w[d], v.y, A.y);
    }
    int py = y0 + row, px = x0 + col;
    int p = py * W + px;
    float gc = sg[row + RAD][col + RAD];
    float mI = A.x - c0u * gc;
    float mII = A.y - c0u * gc * gc;
    float iv = 1.f / ((mII - mI * mI) + CRF_EPS);
    float N = Su[px] * Su[py] - c0u;
    float av = mI * (1.f - N) * iv;
    float bv = N - av * mI;
    mean_I[p] = mI; inv_var[p] = iv; a1b1[p] = make_float2(av, bv);
}

__global__ __launch_bounds__(256, 4) void fb_s2(const float2* __restrict__ a1b1,
        const unsigned short* __restrict__ grayh, float* __restrict__ inv_bn,
        W21 wu, float c0u) {
    __shared__ float2 s2[RIN][CIN];
    __shared__ float2 ii[TY][CIN];
    int L = swz(blockIdx.x, NBLK);
    int x0 = (L & (GX - 1)) * TX, y0 = (L >> 4) * TY;
    int t = threadIdx.x;
    for (int i = t; i < RIN * CIN; i += 256) {
        int r = i / CIN, c = i - r * CIN;
        int gx = x0 + c - RAD, gy = y0 + r - RAD;
        float2 v = make_float2(0.f, 0.f);
        if ((unsigned)gx < W && (unsigned)gy < H) v = a1b1[gy * W + gx];
        s2[r][c] = v;
    }
    __syncthreads();
    if (t < NVT) {
        int c = t % CIN, r0 = (t / CIN) * 2;
        float2 acc0 = make_float2(0.f, 0.f), acc1 = acc0;
        #pragma unroll
        for (int s = 0; s < 22; ++s) {
            float2 v = s2[r0 + s][c];
            if (s <= 20) { acc0.x = fmaf(wu.w[s], v.x, acc0.x); acc0.y = fmaf(wu.w[s], v.y, acc0.y); }
            if (s >= 1)  { acc1.x = fmaf(wu.w[s-1], v.x, acc1.x); acc1.y = fmaf(wu.w[s-1], v.y, acc1.y); }
        }
        ii[r0][c] = acc0; ii[r0 + 1][c] = acc1;
    }
    __syncthreads();
    int row = t >> 5, col = t & 31;
    float2 A = make_float2(0.f, 0.f);
    #pragma unroll
    for (int d = 0; d < KS; ++d) {
        float2 v = ii[row][col + d];
        A.x = fmaf(wu.w[d], v.x, A.x);
        A.y = fmaf(wu.w[d], v.y, A.y);
    }
    int p = (y0 + row) * W + x0 + col;
    float2 cen = s2[row + RAD][col + RAD];
    float va = A.x - c0u * cen.x;
    float vb = A.y - c0u * cen.y;
    inv_bn[p] = 1.f / (va * unpackh(grayh[p]) + vb);
}

__global__ __launch_bounds__(256, 4) void fb_f1(const ushort4* __restrict__ Qh,
        const unsigned short* __restrict__ grayh, const float* __restrict__ mean_I,
        const float* __restrict__ inv_var, const float* __restrict__ Sg,
        const float4* __restrict__ unary, ushort4* __restrict__ a_out,
        ushort4* __restrict__ b_out, float4* __restrict__ partial,
        W21 wg, W21 wu, float c0g, float c0u) {
    __shared__ __align__(16) char smem[23296 + 5824 + 6656];
    float4* sQ = (float4*)smem;
    float*  sG = (float*)(smem + 23296);
    float4* i2 = (float4*)(smem + 23296 + 5824);
    float4* i0 = (float4*)smem;
    float4* i1 = (float4*)(smem + 6656);
    int L = swz(blockIdx.x, NBLK);
    int x0 = (L & (GX - 1)) * TX, y0 = (L >> 4) * TY;
    int t = threadIdx.x;
    for (int i = t; i < RIN * CIN; i += 256) {
        int r = i / CIN, c = i - r * CIN;
        int gx = x0 + c - RAD, gy = y0 + r - RAD;
        float4 q = f4(0.f, 0.f, 0.f, 0.f); float g = 0.f;
        if ((unsigned)gx < W && (unsigned)gy < H) {
            int p = gy * W + gx; q = unpack4(Qh[p]); g = unpackh(grayh[p]);
        }
        sQ[i] = q; sG[i] = g;
    }
    __syncthreads();
    int row = t >> 5, col = t & 31;
    int py = y0 + row, px = x0 + col;
    int p = py * W + px;
    float mI = mean_I[p], iv = inv_var[p];
    float4 u = unary[p];
    float sgx = Sg[px], sgy = Sg[py];
    float4 Qc = sQ[(row + RAD) * CIN + col + RAD];
    float  gc = sG[(row + RAD) * CIN + col + RAD];
    float4 a0[2], a1[2], a2[2];
    int vc = t % CIN, vr0 = (t / CIN) * 2;
    if (t < NVT) {
        #pragma unroll
        for (int j = 0; j < 2; ++j) { a0[j] = f4(0,0,0,0); a1[j] = a0[j]; a2[j] = a0[j]; }
        #pragma unroll
        for (int s = 0; s < 22; ++s) {
            float4 q = sQ[(vr0 + s) * CIN + vc];
            float g = sG[(vr0 + s) * CIN + vc];
            float4 gq = f4(g * q.x, g * q.y, g * q.z, g * q.w);
            if (s <= 20) {
                a0[0] = fma4(wg.w[s], q, a0[0]);
                a1[0] = fma4(wu.w[s], q, a1[0]);
                a2[0] = fma4(wu.w[s], gq, a2[0]);
            }
            if (s >= 1) {
                a0[1] = fma4(wg.w[s-1], q, a0[1]);
                a1[1] = fma4(wu.w[s-1], q, a1[1]);
                a2[1] = fma4(wu.w[s-1], gq, a2[1]);
            }
        }
    }
    __syncthreads();
    if (t < NVT) {
        #pragma unroll
        for (int j = 0; j < 2; ++j) {
            i0[(vr0 + j) * CIN + vc] = a0[j];
            i1[(vr0 + j) * CIN + vc] = a1[j];
            i2[(vr0 + j) * CIN + vc] = a2[j];
        }
    }
    __syncthreads();
    float4 A0 = f4(0,0,0,0), A1 = A0, A2 = A0;
    #pragma unroll
    for (int d = 0; d < KS; ++d) {
        A0 = fma4(wg.w[d], i0[row * CIN + col + d], A0);
        A1 = fma4(wu.w[d], i1[row * CIN + col + d], A1);
        A2 = fma4(wu.w[d], i2[row * CIN + col + d], A2);
    }
    float4 g4  = fma4(-c0g, Qc, A0);
    float4 m4  = fma4(-c0u, Qc, A1);
    float4 mi4 = fma4(-c0u * gc, Qc, A2);
    float4 a, b;
    a.x = (mi4.x - mI * m4.x) * iv; a.y = (mi4.y - mI * m4.y) * iv;
    a.z = (mi4.z - mI * m4.z) * iv; a.w = (mi4.w - mI * m4.w) * iv;
    b.x = m4.x - a.x * mI; b.y = m4.y - a.y * mI;
    b.z = m4.z - a.z * mI; b.w = m4.w - a.w * mI;
    float s3 = 3.f / (sgx * sgy - c0g);
    float4 part = f4(fmaf(s3, g4.x, -u.x), fmaf(s3, g4.y, -u.y),
                     fmaf(s3, g4.z, -u.z), fmaf(s3, g4.w, -u.w));
    a_out[p] = pack4(a); b_out[p] = pack4(b); partial[p] = part;
}

__global__ __launch_bounds__(256, 4) void fb_f2(const ushort4* __restrict__ A,
        const ushort4* __restrict__ B, const float4* __restrict__ partial,
        const unsigned short* __restrict__ grayh, const float* __restrict__ inv_bn,
        float4* __restrict__ QoutF, ushort4* __restrict__ QoutH, int last,
        W21 wu, float c0u) {
    __shared__ __align__(16) char smem[23296 + 6656];
    float4* sT = (float4*)smem;
    float4* ia = (float4*)(smem + 23296);
    float4* ib = (float4*)smem;
    int L = swz(blockIdx.x, NBLK);
    int x0 = (L & (GX - 1)) * TX, y0 = (L >> 4) * TY;
    int t = threadIdx.x;
    int row = t >> 5, col = t & 31;
    int py = y0 + row, px = x0 + col;
    int p = py * W + px;
    int vc = t % CIN, vr0 = (t / CIN) * 2;
    float gv = unpackh(grayh[p]);
    float ibn = 10.f * inv_bn[p];
    float4 part = partial[p];
    for (int i = t; i < RIN * CIN; i += 256) {
        int r = i / CIN, c = i - r * CIN;
        int gx = x0 + c - RAD, gy = y0 + r - RAD;
        float4 v = f4(0.f, 0.f, 0.f, 0.f);
        if ((unsigned)gx < W && (unsigned)gy < H) v = unpack4(A[gy * W + gx]);
        sT[i] = v;
    }
    __syncthreads();
    float4 Ac = sT[(row + RAD) * CIN + col + RAD];
    float4 va0 = f4(0,0,0,0), va1 = va0;
    if (t < NVT) {
        #pragma unroll
        for (int s = 0; s < 22; ++s) {
            float4 v = sT[(vr0 + s) * CIN + vc];
            if (s <= 20) va0 = fma4(wu.w[s], v, va0);
            if (s >= 1)  va1 = fma4(wu.w[s-1], v, va1);
        }
        ia[vr0 * CIN + vc] = va0;
        ia[(vr0 + 1) * CIN + vc] = va1;
    }
    __syncthreads();
    for (int i = t; i < RIN * CIN; i += 256) {
        int r = i / CIN, c = i - r * CIN;
        int gx = x0 + c - RAD, gy = y0 + r - RAD;
        float4 v = f4(0.f, 0.f, 0.f, 0.f);
        if ((unsigned)gx < W && (unsigned)gy < H) v = unpack4(B[gy * W + gx]);
        sT[i] = v;
    }
    __syncthreads();
    float4 Bc = sT[(row + RAD) * CIN + col + RAD];
    float4 vb0 = f4(0,0,0,0), vb1 = vb0;
    if (t < NVT) {
        #pragma unroll
        for (int s = 0; s < 22; ++s) {
            float4 v = sT[(vr0 + s) * CIN + vc];
            if (s <= 20) vb0 = fma4(wu.w[s], v, vb0);
            if (s >= 1)  vb1 = fma4(wu.w[s-1], v, vb1);
        }
    }
    __syncthreads();
    if (t < NVT) {
        ib[vr0 * CIN + vc] = vb0;
        ib[(vr0 + 1) * CIN + vc] = vb1;
    }
    __syncthreads();
    float4 VA = f4(0,0,0,0), VB = VA;
    #pragma unroll
    for (int d = 0; d < KS; ++d) {
        VA = fma4(wu.w[d], ia[row * CIN + col + d], VA);
        VB = fma4(wu.w[d], ib[row * CIN + col + d], VB);
    }
    float4 a4 = fma4(-c0u, Ac, VA);
    float4 b4 = fma4(-c0u, Bc, VB);
    float lx = fmaf(fmaf(a4.x, gv, b4.x), ibn, part.x);
    float ly = fmaf(fmaf(a4.y, gv, b4.y), ibn, part.y);
    float lz = fmaf(fmaf(a4.z, gv, b4.z), ibn, part.z);
    float lw = fmaf(fmaf(a4.w, gv, b4.w), ibn, part.w);
    float m = fmaxf(fmaxf(lx, ly), fmaxf(lz, lw));
    float ex = expf(lx - m), ey = expf(ly - m), ez = expf(lz - m), ew = expf(lw - m);
    float inv = 1.f / (ex + ey + ez + ew);
    float4 qn = f4(ex * inv, ey * inv, ez * inv, ew * inv);
    if (last) QoutF[p] = qn;
    else      QoutH[p] = pack4(qn);
}

// ---- host ----

static void make_w_host(double theta, W21* w, float* c0) {
    double tmp[KS], s = 0.0;
    for (int d = -RAD; d <= RAD; ++d) {
        double v = exp(-(double)(d * d) / (2.0 * theta * theta));
        tmp[d + RAD] = v; s += v;
    }
    for (int i = 0; i < KS; ++i) w->w[i] = (float)(tmp[i] / s);
    *c0 = (float)(1.0 / (s * s));   // normalized 2D center weight
}

extern "C" void kernel_launch(void* const* d_in, const int* in_sizes, int n_in,
                              void* d_out, int out_size, void* d_ws, size_t ws_size,
                              hipStream_t stream) {
    const float4* unary = (const float4*)d_in[0];
    const float* image = (const float*)d_in[1];
    char* wsb = (char*)d_ws;

    ushort4* qA      = (ushort4*)wsb;                              // 2 MB
    ushort4* qB      = (ushort4*)(wsb + 2097152);                  // 2 MB
    ushort4* aA      = (ushort4*)(wsb + 4194304);                  // 2 MB
    ushort4* aB      = (ushort4*)(wsb + 6291456);                  // 2 MB
    ushort4* bA      = (ushort4*)(wsb + 8388608);                  // 2 MB
    ushort4* bB      = (ushort4*)(wsb + 10485760);                 // 2 MB
    unsigned short* grayh = (unsigned short*)(wsb + 12582912);     // 0.5 MB
    float2*  a1b1    = (float2*)(wsb + 13107200);                  // 2 MB
    float4*  partial = (float4*)(wsb + 15204352);                  // 4 MB (fb)
    float*   mean_I  = (float*)(wsb + 19398656);                   // 1 MB (fb)
    float*   inv_var = (float*)(wsb + 20447232);                   // 1 MB (fb)
    float*   inv_bn  = (float*)(wsb + 21495808);                   // 1 MB (fb)
    float*   Sg      = (float*)(wsb + 22544384);
    float*   Su      = (float*)(wsb + 22546432);
    int*     flag_q  = (int*)(wsb + 22548480);                     // 4 KB
    int*     flag_ab = (int*)(wsb + 22552576);                     // 4 KB

    W21 wg, wu; float c0g, c0u;
    make_w_host(2.5, &wg, &c0g);
    make_w_host(10.0 / 3.0, &wu, &c0u);

    // deterministic cooperative-capacity pre-check (host-only, capture-safe)
    int dev = 0;
    (void)hipGetDevice(&dev);
    int coop = 0, nCU = 0, blkPerCU = 0;
    (void)hipDeviceGetAttribute(&coop, hipDeviceAttributeCooperativeLaunch, dev);
    (void)hipDeviceGetAttribute(&nCU, hipDeviceAttributeMultiprocessorCount, dev);
    (void)hipOccupancyMaxActiveBlocksPerMultiprocessor(&blkPerCU,
            (const void*)k_crf, 256, 0);
    bool useCoop = (coop != 0) && ((long)blkPerCU * nCU >= NBLK);

    hipError_t st = hipErrorUnknown;
    if (useCoop) {
        Params P;
        P.unary = unary; P.image = image; P.grayh = grayh;
        P.qA = qA; P.qB = qB; P.a1b1 = a1b1;
        P.aA = aA; P.aB = aB; P.bA = bA; P.bB = bB;
        P.Qfinal = (float4*)d_out;
        P.flag_q = flag_q; P.flag_ab = flag_ab;
        P.wg = wg; P.wu = wu; P.c0g = c0g; P.c0u = c0u;
        void* args[] = { &P };
        st = hipLaunchCooperativeKernel((const void*)k_crf, dim3(NBLK), dim3(256),
                                        args, 0, stream);
    }
    if (st != hipSuccess) {
        dim3 bl(256), grEl(NPIX / 256), grT(NBLK);
        fb_init<<<grEl, bl, 0, stream>>>(image, unary, grayh, qA, Sg, Su, wg, wu);
        fb_s1<<<grT, bl, 0, stream>>>(grayh, Su, mean_I, inv_var, a1b1, wu, c0u);
        fb_s2<<<grT, bl, 0, stream>>>(a1b1, grayh, inv_bn, wu, c0u);
        for (int it = 0; it < 5; ++it) {
            fb_f1<<<grT, bl, 0, stream>>>(qA, grayh, mean_I, inv_var, Sg,
                                          unary, aA, bA, partial, wg, wu, c0g, c0u);
            fb_f2<<<grT, bl, 0, stream>>>(aA, bA, partial, grayh, inv_bn,
                                          (float4*)d_out, qA, (it == 4) ? 1 : 0,
                                          wu, c0u);
        }
    }
}